// Round 12
// baseline (292.517 us; speedup 1.0000x reference)
//
#include <hip/hip_runtime.h>

#define NN 100000
#define NE 600000
#define DD 128
#define SCAN_CHUNK 2048
#define NCHUNK 49  /* ceil(NN / SCAN_CHUNK) */

typedef __attribute__((ext_vector_type(8))) short bf8;
typedef __attribute__((ext_vector_type(4))) float f4;
typedef __attribute__((ext_vector_type(4))) unsigned short us4;
typedef __attribute__((ext_vector_type(8))) unsigned short us8;

__device__ __forceinline__ float frelu(float x) { return x > 0.f ? x : 0.f; }

__device__ __forceinline__ unsigned short f2b(float f)
{
    union { float f; unsigned int i; } c;
    c.f = f;
    unsigned int u = c.i;
    return (unsigned short)((u + 0x7fffu + ((u >> 16) & 1u)) >> 16);
}

// unpack a u32 of 2 bf16 into float2 {lo, hi} (enables v_pk_add_f32 accumulate)
__device__ __forceinline__ float2 up2(unsigned int v)
{
    return make_float2(__uint_as_float(v << 16),
                       __uint_as_float(v & 0xffff0000u));
}

// per-wave int64 edge_index detection: odd words of first 64 entries all zero
__device__ __forceinline__ bool is64(const int* __restrict__ ei)
{
    int v = ei[2 * (threadIdx.x & 63) + 1];
    return __ballot(v != 0) == 0ULL;
}

__global__ void k_count(const int* __restrict__ ei, int* __restrict__ deg)
{
    bool w64 = is64(ei);
    int e = blockIdx.x * 256 + threadIdx.x;
    if (e >= NE) return;
    int dst = w64 ? ei[2 * (NE + e)] : ei[NE + e];
    atomicAdd(&deg[dst], 1);
}

__global__ void k_scan1(const int* __restrict__ cnt, int* __restrict__ offs,
                        int* __restrict__ chunks)
{
    __shared__ int sd[256];
    int t = threadIdx.x;
    int base = blockIdx.x * SCAN_CHUNK + t * 8;
    int v[8];
    int s = 0;
    #pragma unroll
    for (int i = 0; i < 8; ++i) {
        int idx = base + i;
        v[i] = (idx < NN) ? cnt[idx] : 0;
        s += v[i];
    }
    sd[t] = s;
    __syncthreads();
    for (int o = 1; o < 256; o <<= 1) {
        int x = (t >= o) ? sd[t - o] : 0;
        __syncthreads();
        sd[t] += x;
        __syncthreads();
    }
    int run = sd[t] - s;
    if (t == 255) chunks[blockIdx.x] = sd[255];
    #pragma unroll
    for (int i = 0; i < 8; ++i) {
        int idx = base + i;
        if (idx < NN) offs[idx] = run;
        run += v[i];
    }
}

__global__ void k_scan2(int* __restrict__ chunks, int* __restrict__ offs)
{
    if (threadIdx.x == 0 && blockIdx.x == 0) {
        int run = 0;
        for (int c = 0; c < NCHUNK; ++c) {
            int v = chunks[c];
            chunks[c] = run;
            run += v;
        }
        offs[NN] = run;
    }
}

__global__ void k_add2(int* __restrict__ offs, const int* __restrict__ chunks,
                       int* __restrict__ cursor, const int* __restrict__ deg,
                       float* __restrict__ deginv)
{
    int i = blockIdx.x * 256 + threadIdx.x;
    if (i >= NN) return;
    int v = offs[i] + chunks[i >> 11];
    offs[i] = v;
    cursor[i] = v;
    int d = deg[i];
    deginv[i] = (d > 0) ? 1.0f / (float)d : 0.0f;
}

__global__ void k_fill(const int* __restrict__ ei, int* __restrict__ cursor,
                       int* __restrict__ csr)
{
    bool w64 = is64(ei);
    int e = blockIdx.x * 256 + threadIdx.x;
    if (e >= NE) return;
    int src = w64 ? ei[2 * e] : ei[e];
    int dst = w64 ? ei[2 * (NE + e)] : ei[NE + e];
    int p = atomicAdd(&cursor[dst], 1);
    csr[p] = src;
}

// Fold BN into weights, emit bf16 W2[l][j][k] (k<128: lin_l, k>=128: lin_r) + fp32 bias.
__global__ void k_fold(const float* __restrict__ lwl, const float* __restrict__ lbl,
                       const float* __restrict__ lwr, const float* __restrict__ bnw,
                       const float* __restrict__ bnb, unsigned short* __restrict__ w2,
                       float* __restrict__ bias)
{
    int id = blockIdx.x * 256 + threadIdx.x;  // 3*128*256 total
    int l = id >> 15;
    int j = (id >> 8) & 127;
    int k = id & 255;
    float inv_std = 1.0f / sqrtf(1.0f + 1e-5f);
    float s = inv_std * bnw[l * 128 + j];
    float w = (k < 128) ? lwl[(l * 128 + j) * 128 + k]
                        : lwr[(l * 128 + j) * 128 + (k - 128)];
    w2[id] = f2b(w * s);
    if (k == 0) bias[l * 128 + j] = lbl[l * 128 + j] * s + bnb[l * 128 + j];
}

// Fused fp32->bf16 convert + column sum (padded gsum: channel c at c*16).
__global__ void k_cvtsum(const float* __restrict__ x, unsigned short* __restrict__ xb,
                         float* __restrict__ gsum)
{
    __shared__ float red[16][128];
    const int t = threadIdx.x;
    const int c8 = (t & 15) * 8;
    const int rg = t >> 4;
    float s[8];
    #pragma unroll
    for (int j = 0; j < 8; ++j) s[j] = 0.f;
    for (int r = blockIdx.x * 16 + rg; r < NN; r += gridDim.x * 16) {
        const f4* p = (const f4*)(x + (size_t)r * 128 + c8);
        f4 a = p[0], b = p[1];
        us8 o;
        o[0] = f2b(a[0]); o[1] = f2b(a[1]); o[2] = f2b(a[2]); o[3] = f2b(a[3]);
        o[4] = f2b(b[0]); o[5] = f2b(b[1]); o[6] = f2b(b[2]); o[7] = f2b(b[3]);
        *(us8*)(xb + (size_t)r * 128 + c8) = o;
        s[0] += a[0]; s[1] += a[1]; s[2] += a[2]; s[3] += a[3];
        s[4] += b[0]; s[5] += b[1]; s[6] += b[2]; s[7] += b[3];
    }
    #pragma unroll
    for (int j = 0; j < 8; ++j) red[rg][c8 + j] = s[j];
    __syncthreads();
    if (t < 128) {
        float v = 0.f;
        #pragma unroll
        for (int g = 0; g < 16; ++g) v += red[g][t];
        atomicAdd(&gsum[t * 16], v);
    }
}

// Quarter-wave (16 lanes) per node. CSR indices preloaded vectorized and
// distributed via __shfl; row loads issue 8-deep independent (one latency
// round for deg<=8 nodes).
__global__ __launch_bounds__(256)
void k_gather(const unsigned short* __restrict__ in,
              const int* __restrict__ offs, const int* __restrict__ csr,
              const float* __restrict__ deginv,
              unsigned short* __restrict__ agg)
{
    const int node = blockIdx.x * 16 + (threadIdx.x >> 4);  // grid exact: NN/16
    const int cq = threadIdx.x & 15;
    const int lane = threadIdx.x & 63;
    const int qbase = lane & ~15;
    int s = offs[node], e = offs[node + 1];
    const int deg = e - s;
    const uint4* bcq = (const uint4*)in + cq;

    float2 a0[4], a1[4];
    #pragma unroll
    for (int j = 0; j < 4; ++j) {
        a0[j] = make_float2(0.f, 0.f);
        a1[j] = make_float2(0.f, 0.f);
    }

    for (int cb = 0; cb < deg; cb += 16) {
        int li = s + cb + cq;
        int idx = csr[(li < e) ? li : (e - 1)];
        int cnt = deg - cb; if (cnt > 16) cnt = 16;
        for (int jb = 0; jb < cnt; jb += 8) {
            int i0 = __shfl(idx, qbase + jb);
            int i1 = __shfl(idx, qbase + jb + 1);
            int i2 = __shfl(idx, qbase + jb + 2);
            int i3 = __shfl(idx, qbase + jb + 3);
            int i4 = __shfl(idx, qbase + jb + 4);
            int i5 = __shfl(idx, qbase + jb + 5);
            int i6 = __shfl(idx, qbase + jb + 6);
            int i7 = __shfl(idx, qbase + jb + 7);
            uint4 z = make_uint4(0u, 0u, 0u, 0u);
            uint4 v0 = bcq[(size_t)i0 * 16];
            uint4 v1 = (jb + 1 < cnt) ? bcq[(size_t)i1 * 16] : z;
            uint4 v2 = (jb + 2 < cnt) ? bcq[(size_t)i2 * 16] : z;
            uint4 v3 = (jb + 3 < cnt) ? bcq[(size_t)i3 * 16] : z;
            uint4 v4 = (jb + 4 < cnt) ? bcq[(size_t)i4 * 16] : z;
            uint4 v5 = (jb + 5 < cnt) ? bcq[(size_t)i5 * 16] : z;
            uint4 v6 = (jb + 6 < cnt) ? bcq[(size_t)i6 * 16] : z;
            uint4 v7 = (jb + 7 < cnt) ? bcq[(size_t)i7 * 16] : z;
            a0[0] += up2(v0.x); a0[1] += up2(v0.y);
            a0[2] += up2(v0.z); a0[3] += up2(v0.w);
            a1[0] += up2(v1.x); a1[1] += up2(v1.y);
            a1[2] += up2(v1.z); a1[3] += up2(v1.w);
            a0[0] += up2(v2.x); a0[1] += up2(v2.y);
            a0[2] += up2(v2.z); a0[3] += up2(v2.w);
            a1[0] += up2(v3.x); a1[1] += up2(v3.y);
            a1[2] += up2(v3.z); a1[3] += up2(v3.w);
            a0[0] += up2(v4.x); a0[1] += up2(v4.y);
            a0[2] += up2(v4.z); a0[3] += up2(v4.w);
            a1[0] += up2(v5.x); a1[1] += up2(v5.y);
            a1[2] += up2(v5.z); a1[3] += up2(v5.w);
            a0[0] += up2(v6.x); a0[1] += up2(v6.y);
            a0[2] += up2(v6.z); a0[3] += up2(v6.w);
            a1[0] += up2(v7.x); a1[1] += up2(v7.y);
            a1[2] += up2(v7.z); a1[3] += up2(v7.w);
        }
    }

    float di = deginv[node];
    us8 o;
    #pragma unroll
    for (int j = 0; j < 4; ++j) {
        float2 t = a0[j] + a1[j];
        o[2 * j]     = f2b(t.x * di);
        o[2 * j + 1] = f2b(t.y * di);
    }
    *(us8*)(agg + (size_t)node * 128 + cq * 8) = o;
}

// MFMA combine (round-3 structure, measured best): out = relu([agg|hin]@W2^T+b),
// h out bf16, colsum into padded gsum. 256 thr = 4 waves; block covers 256 rows
// in 4 groups of 64; W staged once in 64 KB swizzled LDS.
__global__ __launch_bounds__(256, 2)
void k_combine(const unsigned short* __restrict__ aggb,
               const unsigned short* __restrict__ hinb,
               const unsigned short* __restrict__ w2, const float* __restrict__ bias,
               unsigned short* __restrict__ hout, float* __restrict__ gsum, int write_h)
{
    __shared__ unsigned short sW[128 * 256];  // 64 KB, XOR-swizzled 16B chunks
    __shared__ float red[512];
    const int tid = threadIdx.x;
    const int lane = tid & 63, wid = tid >> 6;

    // stage W2 layer (64 KB) into LDS: chunk c of row j at (c*16)^((j&7)<<4)
    {
        const f4* wg = (const f4*)w2;
        #pragma unroll
        for (int it = 0; it < 16; ++it) {
            int idx = it * 256 + tid;       // 0..4095 chunks
            int j = idx >> 5, c = idx & 31;
            f4 v = wg[idx];
            *(f4*)((char*)sW + j * 512 + ((c * 16) ^ ((j & 7) << 4))) = v;
        }
    }
    __syncthreads();

    const int r15 = lane & 15, q = lane >> 4;

    float bb[8][4];
    #pragma unroll
    for (int ct = 0; ct < 8; ++ct)
        #pragma unroll
        for (int r = 0; r < 4; ++r) bb[ct][r] = bias[ct * 16 + q * 4 + r];

    float csum[8][4];
    #pragma unroll
    for (int ct = 0; ct < 8; ++ct)
        #pragma unroll
        for (int r = 0; r < 4; ++r) csum[ct][r] = 0.f;

    #pragma unroll
    for (int grp = 0; grp < 4; ++grp) {
        const int row = blockIdx.x * 256 + grp * 64 + wid * 16 + r15;
        const int rowc = (row < NN) ? row : (NN - 1);
        const bool ok = row < NN;

        f4 acc[8];
        #pragma unroll
        for (int ct = 0; ct < 8; ++ct) acc[ct] = (f4){0.f, 0.f, 0.f, 0.f};

        #pragma unroll
        for (int ks = 0; ks < 8; ++ks) {
            const unsigned short* s = (ks < 4) ? aggb : hinb;
            bf8 bfrag = *(const bf8*)(s + (size_t)rowc * 128 + (ks & 3) * 32 + q * 8);
            #pragma unroll
            for (int ct = 0; ct < 8; ++ct) {
                int j = ct * 16 + r15;
                bf8 wfrag = *(const bf8*)((char*)sW + j * 512 +
                                          ((ks * 64 + q * 16) ^ ((j & 7) << 4)));
                acc[ct] = __builtin_amdgcn_mfma_f32_16x16x32_bf16(wfrag, bfrag, acc[ct], 0, 0, 0);
            }
        }

        #pragma unroll
        for (int ct = 0; ct < 8; ++ct) {
            float o[4];
            #pragma unroll
            for (int r = 0; r < 4; ++r) {
                float v = frelu(acc[ct][r] + bb[ct][r]);
                o[r] = ok ? v : 0.f;
                csum[ct][r] += o[r];
            }
            if (ok && write_h) {
                us4 p;
                p[0] = f2b(o[0]); p[1] = f2b(o[1]); p[2] = f2b(o[2]); p[3] = f2b(o[3]);
                *(us4*)(hout + (size_t)row * 128 + ct * 16 + q * 4) = p;
            }
        }
    }

    // reduce column sums over the 16 rows (lanes r15) per q-group
    #pragma unroll
    for (int ct = 0; ct < 8; ++ct)
        #pragma unroll
        for (int r = 0; r < 4; ++r) {
            float v = csum[ct][r];
            v += __shfl_xor(v, 1);
            v += __shfl_xor(v, 2);
            v += __shfl_xor(v, 4);
            v += __shfl_xor(v, 8);
            csum[ct][r] = v;
        }

    if (r15 == 0) {
        #pragma unroll
        for (int ct = 0; ct < 8; ++ct)
            #pragma unroll
            for (int r = 0; r < 4; ++r)
                red[wid * 128 + ct * 16 + q * 4 + r] = csum[ct][r];
    }
    __syncthreads();
    if (tid < 128) {
        float s = red[tid] + red[128 + tid] + red[256 + tid] + red[384 + tid];
        atomicAdd(&gsum[tid * 16], s);
    }
}

__global__ void k_mlp(const float* __restrict__ gsum,
                      const float* __restrict__ fc1w, const float* __restrict__ fc1b,
                      const float* __restrict__ fc2w, const float* __restrict__ fc2b,
                      const float* __restrict__ fc3w, const float* __restrict__ fc3b,
                      float* __restrict__ out)
{
    __shared__ float g[128], t1[256], t2[128];
    int t = threadIdx.x;
    if (t < 128) g[t] = gsum[t * 16];
    __syncthreads();
    float a = fc1b[t];
    for (int k = 0; k < 128; ++k) a += fc1w[t * 128 + k] * g[k];
    t1[t] = frelu(a);
    __syncthreads();
    if (t < 128) {
        float a2 = fc2b[t];
        for (int k = 0; k < 256; ++k) a2 += fc2w[t * 256 + k] * t1[k];
        t2[t] = frelu(a2);
    }
    __syncthreads();
    if (t < 64) {
        float s = t2[t] * fc3w[t] + t2[t + 64] * fc3w[t + 64];
        for (int o = 32; o; o >>= 1) s += __shfl_down(s, o);
        if (t == 0) out[0] = s + fc3b[0];
    }
}

extern "C" void kernel_launch(void* const* d_in, const int* in_sizes, int n_in,
                              void* d_out, int out_size, void* d_ws, size_t ws_size,
                              hipStream_t stream)
{
    const float* x    = (const float*)d_in[0];
    const int*   ei   = (const int*)d_in[1];
    const float* lwl  = (const float*)d_in[2];
    const float* lbl  = (const float*)d_in[3];
    const float* lwr  = (const float*)d_in[4];
    const float* bnw  = (const float*)d_in[5];
    const float* bnb  = (const float*)d_in[6];
    const float* fc1w = (const float*)d_in[7];
    const float* fc1b = (const float*)d_in[8];
    const float* fc2w = (const float*)d_in[9];
    const float* fc2b = (const float*)d_in[10];
    const float* fc3w = (const float*)d_in[11];
    const float* fc3b = (const float*)d_in[12];
    float* out = (float*)d_out;

    char* ws = (char*)d_ws;
    size_t off = 0;
    auto alloc = [&](size_t b) -> char* {
        char* p = ws + off;
        off = (off + b + 255) & ~(size_t)255;
        return p;
    };
    int*   deg_cnt = (int*)alloc((size_t)NN * 4);
    int*   offs    = (int*)alloc((size_t)(NN + 1) * 4);
    int*   cursor  = (int*)alloc((size_t)NN * 4);
    int*   chunks  = (int*)alloc(64 * 4);
    int*   csr     = (int*)alloc((size_t)NE * 4);
    float* deginv  = (float*)alloc((size_t)NN * 4);
    unsigned short* w2   = (unsigned short*)alloc((size_t)3 * 128 * 256 * 2);
    float* bias    = (float*)alloc((size_t)3 * 128 * 4);
    float* gsum    = (float*)alloc(128 * 16 * 4);   // padded: channel c at c*16
    unsigned short* xbf  = (unsigned short*)alloc((size_t)NN * 128 * 2);
    unsigned short* hA   = (unsigned short*)alloc((size_t)NN * 128 * 2);
    unsigned short* hB   = (unsigned short*)alloc((size_t)NN * 128 * 2);
    unsigned short* agg  = (unsigned short*)alloc((size_t)NN * 128 * 2);

    hipMemsetAsync(deg_cnt, 0, (size_t)NN * 4, stream);
    hipMemsetAsync(gsum, 0, 128 * 16 * 4, stream);

    k_count<<<(NE + 255) / 256, 256, 0, stream>>>(ei, deg_cnt);
    k_scan1<<<NCHUNK, 256, 0, stream>>>(deg_cnt, offs, chunks);
    k_scan2<<<1, 64, 0, stream>>>(chunks, offs);
    k_add2<<<(NN + 255) / 256, 256, 0, stream>>>(offs, chunks, cursor, deg_cnt, deginv);
    k_fill<<<(NE + 255) / 256, 256, 0, stream>>>(ei, cursor, csr);
    k_fold<<<(3 * 128 * 256) / 256, 256, 0, stream>>>(lwl, lbl, lwr, bnw, bnb, w2, bias);
    k_cvtsum<<<512, 256, 0, stream>>>(x, xbf, gsum);

    const unsigned short* hin = xbf;
    unsigned short* houts[3] = {hA, hB, hA};
    for (int l = 0; l < 3; ++l) {
        k_gather<<<NN / 16, 256, 0, stream>>>(hin, offs, csr, deginv, agg);
        k_combine<<<(NN + 255) / 256, 256, 0, stream>>>(
            agg, hin, w2 + (size_t)l * 128 * 256, bias + (size_t)l * 128,
            houts[l], gsum, (l < 2) ? 1 : 0);
        hin = houts[l];
    }
    k_mlp<<<1, 256, 0, stream>>>(gsum, fc1w, fc1b, fc2w, fc2b, fc3w, fc3b, out);
}

// Round 13
// 260.834 us; speedup vs baseline: 1.1215x; 1.1215x over previous
//
#include <hip/hip_runtime.h>

#define NN 100000
#define NE 600000
#define DD 128
#define SCAN_CHUNK 2048
#define NCHUNK 49  /* ceil(NN / SCAN_CHUNK) */

typedef __attribute__((ext_vector_type(8))) short bf8;
typedef __attribute__((ext_vector_type(4))) float f4;
typedef __attribute__((ext_vector_type(4))) unsigned short us4;
typedef __attribute__((ext_vector_type(8))) unsigned short us8;

__device__ __forceinline__ float frelu(float x) { return x > 0.f ? x : 0.f; }

__device__ __forceinline__ unsigned short f2b(float f)
{
    union { float f; unsigned int i; } c;
    c.f = f;
    unsigned int u = c.i;
    return (unsigned short)((u + 0x7fffu + ((u >> 16) & 1u)) >> 16);
}

// unpack a u32 of 2 bf16 into float2 {lo, hi} (enables v_pk_add_f32 accumulate)
__device__ __forceinline__ float2 up2(unsigned int v)
{
    return make_float2(__uint_as_float(v << 16),
                       __uint_as_float(v & 0xffff0000u));
}

// per-wave int64 edge_index detection: odd words of first 64 entries all zero
__device__ __forceinline__ bool is64(const int* __restrict__ ei)
{
    int v = ei[2 * (threadIdx.x & 63) + 1];
    return __ballot(v != 0) == 0ULL;
}

__global__ void k_count(const int* __restrict__ ei, int* __restrict__ deg)
{
    bool w64 = is64(ei);
    int e = blockIdx.x * 256 + threadIdx.x;
    if (e >= NE) return;
    int dst = w64 ? ei[2 * (NE + e)] : ei[NE + e];
    atomicAdd(&deg[dst], 1);
}

__global__ void k_scan1(const int* __restrict__ cnt, int* __restrict__ offs,
                        int* __restrict__ chunks)
{
    __shared__ int sd[256];
    int t = threadIdx.x;
    int base = blockIdx.x * SCAN_CHUNK + t * 8;
    int v[8];
    int s = 0;
    #pragma unroll
    for (int i = 0; i < 8; ++i) {
        int idx = base + i;
        v[i] = (idx < NN) ? cnt[idx] : 0;
        s += v[i];
    }
    sd[t] = s;
    __syncthreads();
    for (int o = 1; o < 256; o <<= 1) {
        int x = (t >= o) ? sd[t - o] : 0;
        __syncthreads();
        sd[t] += x;
        __syncthreads();
    }
    int run = sd[t] - s;
    if (t == 255) chunks[blockIdx.x] = sd[255];
    #pragma unroll
    for (int i = 0; i < 8; ++i) {
        int idx = base + i;
        if (idx < NN) offs[idx] = run;
        run += v[i];
    }
}

__global__ void k_scan2(int* __restrict__ chunks, int* __restrict__ offs)
{
    if (threadIdx.x == 0 && blockIdx.x == 0) {
        int run = 0;
        for (int c = 0; c < NCHUNK; ++c) {
            int v = chunks[c];
            chunks[c] = run;
            run += v;
        }
        offs[NN] = run;
    }
}

__global__ void k_add2(int* __restrict__ offs, const int* __restrict__ chunks,
                       int* __restrict__ cursor, const int* __restrict__ deg,
                       float* __restrict__ deginv)
{
    int i = blockIdx.x * 256 + threadIdx.x;
    if (i >= NN) return;
    int v = offs[i] + chunks[i >> 11];
    offs[i] = v;
    cursor[i] = v;
    int d = deg[i];
    deginv[i] = (d > 0) ? 1.0f / (float)d : 0.0f;
}

__global__ void k_fill(const int* __restrict__ ei, int* __restrict__ cursor,
                       int* __restrict__ csr)
{
    bool w64 = is64(ei);
    int e = blockIdx.x * 256 + threadIdx.x;
    if (e >= NE) return;
    int src = w64 ? ei[2 * e] : ei[e];
    int dst = w64 ? ei[2 * (NE + e)] : ei[NE + e];
    int p = atomicAdd(&cursor[dst], 1);
    csr[p] = src;
}

// Fold BN into weights, emit bf16 W2[l][j][k] (k<128: lin_l, k>=128: lin_r) + fp32 bias.
__global__ void k_fold(const float* __restrict__ lwl, const float* __restrict__ lbl,
                       const float* __restrict__ lwr, const float* __restrict__ bnw,
                       const float* __restrict__ bnb, unsigned short* __restrict__ w2,
                       float* __restrict__ bias)
{
    int id = blockIdx.x * 256 + threadIdx.x;  // 3*128*256 total
    int l = id >> 15;
    int j = (id >> 8) & 127;
    int k = id & 255;
    float inv_std = 1.0f / sqrtf(1.0f + 1e-5f);
    float s = inv_std * bnw[l * 128 + j];
    float w = (k < 128) ? lwl[(l * 128 + j) * 128 + k]
                        : lwr[(l * 128 + j) * 128 + (k - 128)];
    w2[id] = f2b(w * s);
    if (k == 0) bias[l * 128 + j] = lbl[l * 128 + j] * s + bnb[l * 128 + j];
}

// Fused fp32->bf16 convert + column sum (padded gsum: channel c at c*16).
__global__ void k_cvtsum(const float* __restrict__ x, unsigned short* __restrict__ xb,
                         float* __restrict__ gsum)
{
    __shared__ float red[16][128];
    const int t = threadIdx.x;
    const int c8 = (t & 15) * 8;
    const int rg = t >> 4;
    float s[8];
    #pragma unroll
    for (int j = 0; j < 8; ++j) s[j] = 0.f;
    for (int r = blockIdx.x * 16 + rg; r < NN; r += gridDim.x * 16) {
        const f4* p = (const f4*)(x + (size_t)r * 128 + c8);
        f4 a = p[0], b = p[1];
        us8 o;
        o[0] = f2b(a[0]); o[1] = f2b(a[1]); o[2] = f2b(a[2]); o[3] = f2b(a[3]);
        o[4] = f2b(b[0]); o[5] = f2b(b[1]); o[6] = f2b(b[2]); o[7] = f2b(b[3]);
        *(us8*)(xb + (size_t)r * 128 + c8) = o;
        s[0] += a[0]; s[1] += a[1]; s[2] += a[2]; s[3] += a[3];
        s[4] += b[0]; s[5] += b[1]; s[6] += b[2]; s[7] += b[3];
    }
    #pragma unroll
    for (int j = 0; j < 8; ++j) red[rg][c8 + j] = s[j];
    __syncthreads();
    if (t < 128) {
        float v = 0.f;
        #pragma unroll
        for (int g = 0; g < 16; ++g) v += red[g][t];
        atomicAdd(&gsum[t * 16], v);
    }
}

// Quarter-wave (16 lanes) per node. CSR indices preloaded vectorized and
// distributed via __shfl; row loads issue 4-deep independent. (Round-10 body,
// measured best: 8-deep regressed ~10 us/layer on deg~6 graphs.)
__global__ __launch_bounds__(256)
void k_gather(const unsigned short* __restrict__ in,
              const int* __restrict__ offs, const int* __restrict__ csr,
              const float* __restrict__ deginv,
              unsigned short* __restrict__ agg)
{
    const int node = blockIdx.x * 16 + (threadIdx.x >> 4);  // grid exact: NN/16
    const int cq = threadIdx.x & 15;
    const int lane = threadIdx.x & 63;
    const int qbase = lane & ~15;
    int s = offs[node], e = offs[node + 1];
    const int deg = e - s;
    const uint4* bcq = (const uint4*)in + cq;

    float2 a0[4], a1[4];
    #pragma unroll
    for (int j = 0; j < 4; ++j) {
        a0[j] = make_float2(0.f, 0.f);
        a1[j] = make_float2(0.f, 0.f);
    }

    for (int cb = 0; cb < deg; cb += 16) {
        int li = s + cb + cq;
        int idx = csr[(li < e) ? li : (e - 1)];
        int cnt = deg - cb; if (cnt > 16) cnt = 16;
        for (int jb = 0; jb < cnt; jb += 4) {
            int i0 = __shfl(idx, qbase + jb);
            int i1 = __shfl(idx, qbase + jb + 1);
            int i2 = __shfl(idx, qbase + jb + 2);
            int i3 = __shfl(idx, qbase + jb + 3);
            uint4 v0 = bcq[(size_t)i0 * 16];
            uint4 v1 = make_uint4(0u, 0u, 0u, 0u);
            uint4 v2 = make_uint4(0u, 0u, 0u, 0u);
            uint4 v3 = make_uint4(0u, 0u, 0u, 0u);
            if (jb + 1 < cnt) v1 = bcq[(size_t)i1 * 16];
            if (jb + 2 < cnt) v2 = bcq[(size_t)i2 * 16];
            if (jb + 3 < cnt) v3 = bcq[(size_t)i3 * 16];
            a0[0] += up2(v0.x); a0[1] += up2(v0.y);
            a0[2] += up2(v0.z); a0[3] += up2(v0.w);
            a1[0] += up2(v1.x); a1[1] += up2(v1.y);
            a1[2] += up2(v1.z); a1[3] += up2(v1.w);
            a0[0] += up2(v2.x); a0[1] += up2(v2.y);
            a0[2] += up2(v2.z); a0[3] += up2(v2.w);
            a1[0] += up2(v3.x); a1[1] += up2(v3.y);
            a1[2] += up2(v3.z); a1[3] += up2(v3.w);
        }
    }

    float di = deginv[node];
    us8 o;
    #pragma unroll
    for (int j = 0; j < 4; ++j) {
        float2 t = a0[j] + a1[j];
        o[2 * j]     = f2b(t.x * di);
        o[2 * j + 1] = f2b(t.y * di);
    }
    *(us8*)(agg + (size_t)node * 128 + cq * 8) = o;
}

// MFMA combine (round-3 structure, measured best): out = relu([agg|hin]@W2^T+b),
// h out bf16, colsum into padded gsum. 256 thr = 4 waves; block covers 256 rows
// in 4 groups of 64; W staged once in 64 KB swizzled LDS.
__global__ __launch_bounds__(256, 2)
void k_combine(const unsigned short* __restrict__ aggb,
               const unsigned short* __restrict__ hinb,
               const unsigned short* __restrict__ w2, const float* __restrict__ bias,
               unsigned short* __restrict__ hout, float* __restrict__ gsum, int write_h)
{
    __shared__ unsigned short sW[128 * 256];  // 64 KB, XOR-swizzled 16B chunks
    __shared__ float red[512];
    const int tid = threadIdx.x;
    const int lane = tid & 63, wid = tid >> 6;

    // stage W2 layer (64 KB) into LDS: chunk c of row j at (c*16)^((j&7)<<4)
    {
        const f4* wg = (const f4*)w2;
        #pragma unroll
        for (int it = 0; it < 16; ++it) {
            int idx = it * 256 + tid;       // 0..4095 chunks
            int j = idx >> 5, c = idx & 31;
            f4 v = wg[idx];
            *(f4*)((char*)sW + j * 512 + ((c * 16) ^ ((j & 7) << 4))) = v;
        }
    }
    __syncthreads();

    const int r15 = lane & 15, q = lane >> 4;

    float bb[8][4];
    #pragma unroll
    for (int ct = 0; ct < 8; ++ct)
        #pragma unroll
        for (int r = 0; r < 4; ++r) bb[ct][r] = bias[ct * 16 + q * 4 + r];

    float csum[8][4];
    #pragma unroll
    for (int ct = 0; ct < 8; ++ct)
        #pragma unroll
        for (int r = 0; r < 4; ++r) csum[ct][r] = 0.f;

    #pragma unroll
    for (int grp = 0; grp < 4; ++grp) {
        const int row = blockIdx.x * 256 + grp * 64 + wid * 16 + r15;
        const int rowc = (row < NN) ? row : (NN - 1);
        const bool ok = row < NN;

        f4 acc[8];
        #pragma unroll
        for (int ct = 0; ct < 8; ++ct) acc[ct] = (f4){0.f, 0.f, 0.f, 0.f};

        #pragma unroll
        for (int ks = 0; ks < 8; ++ks) {
            const unsigned short* s = (ks < 4) ? aggb : hinb;
            bf8 bfrag = *(const bf8*)(s + (size_t)rowc * 128 + (ks & 3) * 32 + q * 8);
            #pragma unroll
            for (int ct = 0; ct < 8; ++ct) {
                int j = ct * 16 + r15;
                bf8 wfrag = *(const bf8*)((char*)sW + j * 512 +
                                          ((ks * 64 + q * 16) ^ ((j & 7) << 4)));
                acc[ct] = __builtin_amdgcn_mfma_f32_16x16x32_bf16(wfrag, bfrag, acc[ct], 0, 0, 0);
            }
        }

        #pragma unroll
        for (int ct = 0; ct < 8; ++ct) {
            float o[4];
            #pragma unroll
            for (int r = 0; r < 4; ++r) {
                float v = frelu(acc[ct][r] + bb[ct][r]);
                o[r] = ok ? v : 0.f;
                csum[ct][r] += o[r];
            }
            if (ok && write_h) {
                us4 p;
                p[0] = f2b(o[0]); p[1] = f2b(o[1]); p[2] = f2b(o[2]); p[3] = f2b(o[3]);
                *(us4*)(hout + (size_t)row * 128 + ct * 16 + q * 4) = p;
            }
        }
    }

    // reduce column sums over the 16 rows (lanes r15) per q-group
    #pragma unroll
    for (int ct = 0; ct < 8; ++ct)
        #pragma unroll
        for (int r = 0; r < 4; ++r) {
            float v = csum[ct][r];
            v += __shfl_xor(v, 1);
            v += __shfl_xor(v, 2);
            v += __shfl_xor(v, 4);
            v += __shfl_xor(v, 8);
            csum[ct][r] = v;
        }

    if (r15 == 0) {
        #pragma unroll
        for (int ct = 0; ct < 8; ++ct)
            #pragma unroll
            for (int r = 0; r < 4; ++r)
                red[wid * 128 + ct * 16 + q * 4 + r] = csum[ct][r];
    }
    __syncthreads();
    if (tid < 128) {
        float s = red[tid] + red[128 + tid] + red[256 + tid] + red[384 + tid];
        atomicAdd(&gsum[tid * 16], s);
    }
}

__global__ void k_mlp(const float* __restrict__ gsum,
                      const float* __restrict__ fc1w, const float* __restrict__ fc1b,
                      const float* __restrict__ fc2w, const float* __restrict__ fc2b,
                      const float* __restrict__ fc3w, const float* __restrict__ fc3b,
                      float* __restrict__ out)
{
    __shared__ float g[128], t1[256], t2[128];
    int t = threadIdx.x;
    if (t < 128) g[t] = gsum[t * 16];
    __syncthreads();
    float a = fc1b[t];
    for (int k = 0; k < 128; ++k) a += fc1w[t * 128 + k] * g[k];
    t1[t] = frelu(a);
    __syncthreads();
    if (t < 128) {
        float a2 = fc2b[t];
        for (int k = 0; k < 256; ++k) a2 += fc2w[t * 256 + k] * t1[k];
        t2[t] = frelu(a2);
    }
    __syncthreads();
    if (t < 64) {
        float s = t2[t] * fc3w[t] + t2[t + 64] * fc3w[t + 64];
        for (int o = 32; o; o >>= 1) s += __shfl_down(s, o);
        if (t == 0) out[0] = s + fc3b[0];
    }
}

extern "C" void kernel_launch(void* const* d_in, const int* in_sizes, int n_in,
                              void* d_out, int out_size, void* d_ws, size_t ws_size,
                              hipStream_t stream)
{
    const float* x    = (const float*)d_in[0];
    const int*   ei   = (const int*)d_in[1];
    const float* lwl  = (const float*)d_in[2];
    const float* lbl  = (const float*)d_in[3];
    const float* lwr  = (const float*)d_in[4];
    const float* bnw  = (const float*)d_in[5];
    const float* bnb  = (const float*)d_in[6];
    const float* fc1w = (const float*)d_in[7];
    const float* fc1b = (const float*)d_in[8];
    const float* fc2w = (const float*)d_in[9];
    const float* fc2b = (const float*)d_in[10];
    const float* fc3w = (const float*)d_in[11];
    const float* fc3b = (const float*)d_in[12];
    float* out = (float*)d_out;

    char* ws = (char*)d_ws;
    size_t off = 0;
    auto alloc = [&](size_t b) -> char* {
        char* p = ws + off;
        off = (off + b + 255) & ~(size_t)255;
        return p;
    };
    int*   deg_cnt = (int*)alloc((size_t)NN * 4);
    int*   offs    = (int*)alloc((size_t)(NN + 1) * 4);
    int*   cursor  = (int*)alloc((size_t)NN * 4);
    int*   chunks  = (int*)alloc(64 * 4);
    int*   csr     = (int*)alloc((size_t)NE * 4);
    float* deginv  = (float*)alloc((size_t)NN * 4);
    unsigned short* w2   = (unsigned short*)alloc((size_t)3 * 128 * 256 * 2);
    float* bias    = (float*)alloc((size_t)3 * 128 * 4);
    float* gsum    = (float*)alloc(128 * 16 * 4);   // padded: channel c at c*16
    unsigned short* xbf  = (unsigned short*)alloc((size_t)NN * 128 * 2);
    unsigned short* hA   = (unsigned short*)alloc((size_t)NN * 128 * 2);
    unsigned short* hB   = (unsigned short*)alloc((size_t)NN * 128 * 2);
    unsigned short* agg  = (unsigned short*)alloc((size_t)NN * 128 * 2);

    hipMemsetAsync(deg_cnt, 0, (size_t)NN * 4, stream);
    hipMemsetAsync(gsum, 0, 128 * 16 * 4, stream);

    k_count<<<(NE + 255) / 256, 256, 0, stream>>>(ei, deg_cnt);
    k_scan1<<<NCHUNK, 256, 0, stream>>>(deg_cnt, offs, chunks);
    k_scan2<<<1, 64, 0, stream>>>(chunks, offs);
    k_add2<<<(NN + 255) / 256, 256, 0, stream>>>(offs, chunks, cursor, deg_cnt, deginv);
    k_fill<<<(NE + 255) / 256, 256, 0, stream>>>(ei, cursor, csr);
    k_fold<<<(3 * 128 * 256) / 256, 256, 0, stream>>>(lwl, lbl, lwr, bnw, bnb, w2, bias);
    k_cvtsum<<<512, 256, 0, stream>>>(x, xbf, gsum);

    const unsigned short* hin = xbf;
    unsigned short* houts[3] = {hA, hB, hA};
    for (int l = 0; l < 3; ++l) {
        k_gather<<<NN / 16, 256, 0, stream>>>(hin, offs, csr, deginv, agg);
        k_combine<<<(NN + 255) / 256, 256, 0, stream>>>(
            agg, hin, w2 + (size_t)l * 128 * 256, bias + (size_t)l * 128,
            houts[l], gsum, (l < 2) ? 1 : 0);
        hin = houts[l];
    }
    k_mlp<<<1, 256, 0, stream>>>(gsum, fc1w, fc1b, fc2w, fc2b, fc3w, fc3b, out);
}